// Round 14
// baseline (239.557 us; speedup 1.0000x reference)
//
#include <hip/hip_runtime.h>
#include <hip/hip_fp16.h>

#define NN 100000
#define NBKT 196   // ceil(NN/512)
#define BCAP 16384 // slack per bucket (mean 8163, sigma ~90 for E=1.6M)

using f16x8 = __attribute__((ext_vector_type(8))) _Float16;
using f32x4 = __attribute__((ext_vector_type(4))) float;
using u32x4 = __attribute__((ext_vector_type(4))) unsigned;

// ---------------- helpers ----------------
__device__ __forceinline__ void fma4(float4& a, float s, const float4& w) {
  a.x = fmaf(s, w.x, a.x);
  a.y = fmaf(s, w.y, a.y);
  a.z = fmaf(s, w.z, a.z);
  a.w = fmaf(s, w.w, a.w);
}

// a[0..8) += cvt(8 halves)
__device__ __forceinline__ void add8(float* a, uint4 q) {
  const __half2* p = (const __half2*)&q;
#pragma unroll
  for (int j = 0; j < 4; ++j) {
    float2 f = __half22float2(p[j]);
    a[2 * j]     += f.x;
    a[2 * j + 1] += f.y;
  }
}

__device__ __forceinline__ unsigned packh2(float x, float y) {
  __half2 h = __floats2half2_rn(x, y);
  return *(unsigned*)&h;
}

// Stage A + prep fused.
// blocks [0,nA): bin 4096 edges each into NBKT dst-buckets (slack regions).
// blocks [nA,nA+64): W1 -> wt1 fp16 [n][k].  [nA+64,nA+96): W2 -> wt2.
__global__ __launch_bounds__(256) void k_binA(const int* __restrict__ e,
                                              const float* __restrict__ W1,
                                              const float* __restrict__ W2,
                                              _Float16* __restrict__ wt1,
                                              _Float16* __restrict__ wt2,
                                              int* __restrict__ gcur,
                                              unsigned int* __restrict__ tmp,
                                              int E, int nA) {
  const int b = blockIdx.x;
  const int tid = threadIdx.x;
  if (b >= nA) {  // weight conversion
    int wb = b - nA;
    if (wb < 64) {
      int i = wb * 256 + tid;
      int n = i >> 7, k = i & 127;
      wt1[i] = (_Float16)W1[k * 128 + n];
    } else {
      int i = (wb - 64) * 256 + tid;
      int n = i >> 7, k = i & 127;
      wt2[i] = (_Float16)W2[k * 64 + n];
    }
    return;
  }
  __shared__ int cnt[256];
  __shared__ int pcur[256];
  __shared__ int sm_flag;
  cnt[tid] = 0;
  if (tid < 64) {  // wave 0: detect int64 layout (odd words all zero)
    int n64 = E < 64 ? E : 64;
    int odd = (tid < n64) ? e[2 * tid + 1] : 0;
    unsigned long long nz = __ballot(odd != 0);
    if (tid == 0) sm_flag = (nz == 0ull) ? 1 : 0;
  }
  __syncthreads();
  const int m = sm_flag;
  const bool pok = ((E & 1) == 0);
  const int start = b * 4096;
  int ss[16], dd[16];
#pragma unroll
  for (int k = 0; k < 8; ++k) {
    int i = start + 2 * (tid + k * 256);
    int s0 = -1, s1 = -1, d0 = 0, d1 = 0;
    if (i < E) {
      if (m) {
        if (pok) {
          int4 sp = ((const int4*)e)[i >> 1];
          int4 dp = ((const int4*)e)[(E + i) >> 1];
          s0 = sp.x; s1 = sp.z; d0 = dp.x; d1 = dp.z;
        } else {
          s0 = (int)((const long long*)e)[i];
          d0 = (int)((const long long*)e)[E + i];
          if (i + 1 < E) {
            s1 = (int)((const long long*)e)[i + 1];
            d1 = (int)((const long long*)e)[E + i + 1];
          }
        }
      } else {
        if (pok) {
          int2 sp = ((const int2*)e)[i >> 1];
          int2 dp = ((const int2*)(e + E))[i >> 1];
          s0 = sp.x; s1 = sp.y; d0 = dp.x; d1 = dp.y;
        } else {
          s0 = e[i]; d0 = e[E + i];
          if (i + 1 < E) { s1 = e[i + 1]; d1 = e[E + i + 1]; }
        }
      }
      if (i + 1 >= E) s1 = -1;
      atomicAdd(&cnt[d0 >> 9], 1);
      if (s1 >= 0) atomicAdd(&cnt[d1 >> 9], 1);
    }
    ss[2 * k] = s0; dd[2 * k] = d0;
    ss[2 * k + 1] = s1; dd[2 * k + 1] = d1;
  }
  __syncthreads();
  if (tid < NBKT && cnt[tid] > 0)
    pcur[tid] = tid * BCAP + atomicAdd(&gcur[tid], cnt[tid]);
  __syncthreads();
#pragma unroll
  for (int k = 0; k < 16; ++k) {
    if (ss[k] >= 0) {
      int bk = dd[k] >> 9;
      int p = atomicAdd(&pcur[bk], 1);
      tmp[p] = ((unsigned)ss[k] << 9) | (unsigned)(dd[k] & 511);
    }
  }
}

// Stage B (scan fused): per bucket, redundant 196-count scan -> base/total;
// LDS histogram (= deg) -> dinv + rowptr; local scan; place srcs.
__global__ __launch_bounds__(256) void k_binB(const unsigned int* __restrict__ tmp,
                                              const int* __restrict__ gcur,
                                              int* __restrict__ rowptr,
                                              float* __restrict__ dinv,
                                              int* __restrict__ srcs) {
  __shared__ int sbuf[256];
  __shared__ int hist[512];
  __shared__ int lofs[512];
  const int b = blockIdx.x;
  const int tid = threadIdx.x;
  int c = (tid < NBKT) ? gcur[tid] : 0;
  sbuf[tid] = c;
  __syncthreads();
#pragma unroll
  for (int off = 1; off < 256; off <<= 1) {
    int t = (tid >= off) ? sbuf[tid - off] : 0;
    __syncthreads();
    sbuf[tid] += t;
    __syncthreads();
  }
  const int total = sbuf[255];
  const int incl = sbuf[b];
  const int base_b = (b > 0) ? sbuf[b - 1] : 0;
  const int cntb = incl - base_b;
  if (b == 0 && tid == 0) rowptr[NN] = total;
  __syncthreads();
  hist[tid] = 0;
  hist[tid + 256] = 0;
  __syncthreads();
  const int tbeg = b * BCAP;
  const int tend = tbeg + cntb;
  for (int j = tbeg + tid; j < tend; j += 256) atomicAdd(&hist[tmp[j] & 511], 1);
  __syncthreads();
  int a0 = hist[2 * tid], a1 = hist[2 * tid + 1];
  int sv = a0 + a1;
  sbuf[tid] = sv;
  __syncthreads();
#pragma unroll
  for (int off = 1; off < 256; off <<= 1) {
    int t = (tid >= off) ? sbuf[tid - off] : 0;
    __syncthreads();
    sbuf[tid] += t;
    __syncthreads();
  }
  int excl = sbuf[tid] - sv;
  lofs[2 * tid] = excl;
  lofs[2 * tid + 1] = excl + a0;
  __syncthreads();
  for (int i = tid; i < 512; i += 256) {
    int node = (b << 9) + i;
    if (node < NN) {
      rowptr[node] = base_b + lofs[i];
      dinv[node] = rsqrtf((float)(hist[i] + 1));
    }
  }
  __syncthreads();
  for (int j = tbeg + tid; j < tend; j += 256) {
    unsigned v = tmp[j];
    int p = base_b + atomicAdd(&lofs[v & 511], 1);
    srcs[p] = (int)(v >> 9);
  }
}

// GEMM1: hh[M,128] = fp16( dinv[row] * (x @ W1) ), row-major, MFMA.
__global__ __launch_bounds__(256) void k_gemm1(const float* __restrict__ A,
                                               const _Float16* __restrict__ Wt,
                                               const float* __restrict__ dinv,
                                               _Float16* __restrict__ out, int M) {
  constexpr int N = 128, NF = N / 16;
  __shared__ _Float16 As[64 * 136];
  __shared__ _Float16 Bs[N * 136];
  const int tid = threadIdx.x;
  const long long row0 = (long long)blockIdx.x * 64;
#pragma unroll
  for (int t = 0; t < 8; ++t) {
    int i = tid + t * 256;  // 2048 float4
    int m = i >> 5, q = i & 31;
    long long row = row0 + m;
    float4 v = make_float4(0.f, 0.f, 0.f, 0.f);
    if (row < M) v = ((const float4*)A)[row * 32 + q];
    uint2 w2 = make_uint2(packh2(v.x, v.y), packh2(v.z, v.w));
    *(uint2*)&As[m * 136 + q * 4] = w2;
  }
#pragma unroll
  for (int t = 0; t < 8; ++t) {  // 128*128 halves / 8 / 256
    int i = tid + t * 256;
    int n = i >> 4, q = i & 15;
    uint4 v = ((const uint4*)Wt)[i];
    *(uint4*)&Bs[n * 136 + q * 8] = v;
  }
  __syncthreads();
  const int lane = tid & 63;
  const int wrow = (tid >> 6) * 16;
  const int r = lane & 15, g = lane >> 4;
  f32x4 acc[NF] = {};
#pragma unroll
  for (int ks = 0; ks < 4; ++ks) {
    f16x8 av = *(const f16x8*)&As[(wrow + r) * 136 + ks * 32 + g * 8];
#pragma unroll
    for (int cf = 0; cf < NF; ++cf) {
      f16x8 bv = *(const f16x8*)&Bs[(cf * 16 + r) * 136 + ks * 32 + g * 8];
      acc[cf] = __builtin_amdgcn_mfma_f32_16x16x32_f16(av, bv, acc[cf], 0, 0, 0);
    }
  }
#pragma unroll
  for (int q = 0; q < 4; ++q) {
    long long row = row0 + wrow + g * 4 + q;
    if (row < M) {
      float sc = dinv[row];
#pragma unroll
      for (int cf = 0; cf < NF; ++cf)
        out[row * N + cf * 16 + r] = (_Float16)(sc * acc[cf][q]);
    }
  }
}

// Fused gather1 + GEMM2, wave-private rows, no barrier, B from global.
// Per block (64 rows): wave w gathers rows w*16 + rnd*4 + grp into its own
// As rows, then MFMAs those same 16 rows against wt2 (L1-resident, loaded
// per-fragment from global):  h2[m,0:64] = fp16( dinv[m] * (As @ W2) ).
// h is the pre-scaled layer-1 table (row-major fp16, 128 ch).
__global__ __launch_bounds__(256) void k_g1g2(const int* __restrict__ rowptr,
                                              const int* __restrict__ srcs,
                                              const float* __restrict__ dinv,
                                              const _Float16* __restrict__ h,
                                              const float* __restrict__ b1,
                                              const _Float16* __restrict__ wt2,
                                              _Float16* __restrict__ h2, int M) {
  __shared__ _Float16 As[64 * 136];
  const int tid = threadIdx.x;
  const int lane = tid & 63;
  const int wave = tid >> 6;
  const int wrow = wave * 16;
  const long long row0 = (long long)blockIdx.x * 64;
  // ---- gather phase: 16 lanes/node, 4 nodes/round, 4 rounds -> 16 rows/wave
  const int grp = lane >> 4;
  const int li = lane & 15;
  const float4* b4 = (const float4*)b1;
  const float4 bb0 = b4[li * 2], bb1 = b4[li * 2 + 1];
#pragma unroll
  for (int rnd = 0; rnd < 4; ++rnd) {
    const int m = wrow + rnd * 4 + grp;
    const long long node = row0 + m;
    uint4 w = make_uint4(0, 0, 0, 0);
    if (node < M) {
      const float dd = dinv[node];
      float acc[8];
      {
        uint4 q0 = *(const uint4*)(h + node * 128 + li * 8);
        const __half2* p = (const __half2*)&q0;
#pragma unroll
        for (int j = 0; j < 4; ++j) {
          float2 f = __half22float2(p[j]);
          acc[2 * j]     = f.x;
          acc[2 * j + 1] = f.y;
        }
      }
      const int beg = rowptr[node], end = rowptr[node + 1];
      int e = beg;
      for (; e + 4 <= end; e += 4) {
        int s0 = __builtin_nontemporal_load(srcs + e);
        int s1 = __builtin_nontemporal_load(srcs + e + 1);
        int s2 = __builtin_nontemporal_load(srcs + e + 2);
        int s3 = __builtin_nontemporal_load(srcs + e + 3);
        uint4 q0 = *(const uint4*)(h + (long long)s0 * 128 + li * 8);
        uint4 q1 = *(const uint4*)(h + (long long)s1 * 128 + li * 8);
        uint4 q2 = *(const uint4*)(h + (long long)s2 * 128 + li * 8);
        uint4 q3 = *(const uint4*)(h + (long long)s3 * 128 + li * 8);
        add8(acc, q0);
        add8(acc, q1);
        add8(acc, q2);
        add8(acc, q3);
      }
      for (; e < end; ++e) {
        int s0 = __builtin_nontemporal_load(srcs + e);
        uint4 q0 = *(const uint4*)(h + (long long)s0 * 128 + li * 8);
        add8(acc, q0);
      }
      float o[8];
      o[0] = fmaxf(fmaf(dd, acc[0], bb0.x), 0.f);
      o[1] = fmaxf(fmaf(dd, acc[1], bb0.y), 0.f);
      o[2] = fmaxf(fmaf(dd, acc[2], bb0.z), 0.f);
      o[3] = fmaxf(fmaf(dd, acc[3], bb0.w), 0.f);
      o[4] = fmaxf(fmaf(dd, acc[4], bb1.x), 0.f);
      o[5] = fmaxf(fmaf(dd, acc[5], bb1.y), 0.f);
      o[6] = fmaxf(fmaf(dd, acc[6], bb1.z), 0.f);
      o[7] = fmaxf(fmaf(dd, acc[7], bb1.w), 0.f);
      w.x = packh2(o[0], o[1]);
      w.y = packh2(o[2], o[3]);
      w.z = packh2(o[4], o[5]);
      w.w = packh2(o[6], o[7]);
    }
    *(uint4*)&As[m * 136 + li * 8] = w;
  }
  // ---- mfma phase (wave-private rows, no barrier): 16x128 @ 128x64 ----
  const int r = lane & 15, g = lane >> 4;
  f32x4 acc2[4] = {};
#pragma unroll
  for (int ks = 0; ks < 4; ++ks) {
    f16x8 av = *(const f16x8*)&As[(wrow + r) * 136 + ks * 32 + g * 8];
#pragma unroll
    for (int cf = 0; cf < 4; ++cf) {
      f16x8 bv = *(const f16x8*)(wt2 + (cf * 16 + r) * 128 + ks * 32 + g * 8);
      acc2[cf] = __builtin_amdgcn_mfma_f32_16x16x32_f16(av, bv, acc2[cf], 0, 0, 0);
    }
  }
#pragma unroll
  for (int q = 0; q < 4; ++q) {
    long long row = row0 + wrow + g * 4 + q;
    if (row < M) {
      float sc = dinv[row];
#pragma unroll
      for (int cf = 0; cf < 4; ++cf)
        h2[row * 64 + cf * 16 + r] = (_Float16)(sc * acc2[cf][q]);
    }
  }
}

// Layer-2 gather over PRE-SCALED fp16 h2 (row-major, 64 ch):
// out = dd*(sum rows incl. self) + b2, fp32 row-major.
__global__ __launch_bounds__(256) void k_gather2(const int* __restrict__ rowptr,
                                                 const int* __restrict__ srcs,
                                                 const float* __restrict__ dinv,
                                                 const _Float16* __restrict__ h,
                                                 const float* __restrict__ b,
                                                 float* __restrict__ out) {
  constexpr int C = 64;
  const int wave = threadIdx.x >> 6;
  const int lane = threadIdx.x & 63;
  const int grp = lane >> 3;            // 8 nodes per wave
  const int li = lane & 7;              // 8 lanes per node
  const int node = blockIdx.x * 32 + wave * 8 + grp;
  if (node >= NN) return;
  const float dd = dinv[node];
  float acc[8];
  {
    uint4 q = *(const uint4*)(h + (long long)node * C + li * 8);
    const __half2* p = (const __half2*)&q;
#pragma unroll
    for (int j = 0; j < 4; ++j) {
      float2 f = __half22float2(p[j]);
      acc[2 * j]     = f.x;
      acc[2 * j + 1] = f.y;
    }
  }
  const int beg = rowptr[node], end = rowptr[node + 1];
  int e = beg;
  for (; e + 4 <= end; e += 4) {
    int s0 = __builtin_nontemporal_load(srcs + e);
    int s1 = __builtin_nontemporal_load(srcs + e + 1);
    int s2 = __builtin_nontemporal_load(srcs + e + 2);
    int s3 = __builtin_nontemporal_load(srcs + e + 3);
    uint4 q0 = *(const uint4*)(h + (long long)s0 * C + li * 8);
    uint4 q1 = *(const uint4*)(h + (long long)s1 * C + li * 8);
    uint4 q2 = *(const uint4*)(h + (long long)s2 * C + li * 8);
    uint4 q3 = *(const uint4*)(h + (long long)s3 * C + li * 8);
    add8(acc, q0);
    add8(acc, q1);
    add8(acc, q2);
    add8(acc, q3);
  }
  for (; e < end; ++e) {
    uint4 q0 = *(const uint4*)(h + (long long)__builtin_nontemporal_load(srcs + e) * C + li * 8);
    add8(acc, q0);
  }
  const float4* b4 = (const float4*)b;
  float4 bb0 = b4[li * 2], bb1 = b4[li * 2 + 1];
  float* op = out + (long long)node * C + li * 8;
  f32x4 v0, v1;
  v0.x = fmaf(dd, acc[0], bb0.x);
  v0.y = fmaf(dd, acc[1], bb0.y);
  v0.z = fmaf(dd, acc[2], bb0.z);
  v0.w = fmaf(dd, acc[3], bb0.w);
  v1.x = fmaf(dd, acc[4], bb1.x);
  v1.y = fmaf(dd, acc[5], bb1.y);
  v1.z = fmaf(dd, acc[6], bb1.z);
  v1.w = fmaf(dd, acc[7], bb1.w);
  __builtin_nontemporal_store(v0, (f32x4*)op);
  __builtin_nontemporal_store(v1, (f32x4*)(op + 4));
}

// ---------------- fallback (atomic scatter, fp32) kernels ----------------
__global__ void k_zero_i32(int* p, int n) {
  int i = blockIdx.x * 256 + threadIdx.x;
  if (i < n) p[i] = 0;
}

__global__ void k_detect_f(const int* __restrict__ e, int* flag, int E) {
  if (threadIdx.x == 0 && blockIdx.x == 0) {
    int n = E < 64 ? E : 64;
    int m = 1;
    for (int i = 0; i < n; ++i)
      if (e[2 * i + 1] != 0) { m = 0; break; }
    *flag = m;
  }
}

__global__ void k_deg_count(const int* __restrict__ e, const int* __restrict__ flag,
                            int* __restrict__ deg, int E) {
  int i = blockIdx.x * 256 + threadIdx.x;
  if (i >= E) return;
  int m = *flag;
  int d = m ? e[2 * (E + i)] : e[E + i];
  atomicAdd(&deg[d], 1);
}

__global__ void k_dinv_f(const int* __restrict__ deg, float* __restrict__ dinv) {
  int i = blockIdx.x * 256 + threadIdx.x;
  if (i < NN) dinv[i] = rsqrtf((float)(deg[i] + 1));
}

template <int N, bool RELU>
__global__ __launch_bounds__(256) void k_gemm_v(const float* __restrict__ A,
                                                const float* __restrict__ W,
                                                float* __restrict__ out, int M) {
  constexpr int K4 = 32;
  constexpr int N4 = N / 4;
  constexpr int CG = N4;
  constexpr int ROWS = (256 / CG) * 4;
  __shared__ float4 Wl[128 * N4];
  __shared__ float4 Xl[ROWS * K4];
  const int tid = threadIdx.x;
  const float4* W4 = (const float4*)W;
  for (int i = tid; i < 128 * N4; i += 256) Wl[i] = W4[i];
  const long long row0 = (long long)blockIdx.x * ROWS;
  const float4* A4 = (const float4*)A;
  for (int i = tid; i < ROWS * K4; i += 256) {
    int r = i >> 5;
    long long row = row0 + r;
    float4 v = make_float4(0.f, 0.f, 0.f, 0.f);
    if (row < M) v = A4[row * K4 + (i & 31)];
    if (RELU) {
      v.x = fmaxf(v.x, 0.f); v.y = fmaxf(v.y, 0.f);
      v.z = fmaxf(v.z, 0.f); v.w = fmaxf(v.w, 0.f);
    }
    Xl[i] = v;
  }
  __syncthreads();
  const int c = tid % CG;
  const int rb = (tid / CG) * 4;
  float4 a0 = make_float4(0, 0, 0, 0), a1 = a0, a2 = a0, a3 = a0;
#pragma unroll 4
  for (int k4 = 0; k4 < K4; ++k4) {
    float4 w0 = Wl[(k4 * 4 + 0) * N4 + c];
    float4 w1 = Wl[(k4 * 4 + 1) * N4 + c];
    float4 w2 = Wl[(k4 * 4 + 2) * N4 + c];
    float4 w3 = Wl[(k4 * 4 + 3) * N4 + c];
    float4 x0 = Xl[(rb + 0) * K4 + k4];
    float4 x1 = Xl[(rb + 1) * K4 + k4];
    float4 x2 = Xl[(rb + 2) * K4 + k4];
    float4 x3 = Xl[(rb + 3) * K4 + k4];
    fma4(a0, x0.x, w0); fma4(a0, x0.y, w1); fma4(a0, x0.z, w2); fma4(a0, x0.w, w3);
    fma4(a1, x1.x, w0); fma4(a1, x1.y, w1); fma4(a1, x1.z, w2); fma4(a1, x1.w, w3);
    fma4(a2, x2.x, w0); fma4(a2, x2.y, w1); fma4(a2, x2.z, w2); fma4(a2, x2.w, w3);
    fma4(a3, x3.x, w0); fma4(a3, x3.y, w1); fma4(a3, x3.z, w2); fma4(a3, x3.w, w3);
  }
  float4* O4 = (float4*)out;
  long long row = row0 + rb;
  if (row + 0 < M) O4[(row + 0) * N4 + c] = a0;
  if (row + 1 < M) O4[(row + 1) * N4 + c] = a1;
  if (row + 2 < M) O4[(row + 2) * N4 + c] = a2;
  if (row + 3 < M) O4[(row + 3) * N4 + c] = a3;
}

template <int C>
__global__ void k_self_bias(const float* __restrict__ h, const float* __restrict__ dinv,
                            const float* __restrict__ b, float* __restrict__ out) {
  constexpr int C4 = C / 4;
  int gid = blockIdx.x * 256 + threadIdx.x;
  if (gid >= NN * C4) return;
  int node = gid / C4;
  int cq = gid % C4;
  float di = dinv[node];
  float sc = di * di;
  float4 v = ((const float4*)h)[gid];
  float4 bb = ((const float4*)b)[cq];
  float4 o;
  o.x = fmaf(v.x, sc, bb.x);
  o.y = fmaf(v.y, sc, bb.y);
  o.z = fmaf(v.z, sc, bb.z);
  o.w = fmaf(v.w, sc, bb.w);
  ((float4*)out)[gid] = o;
}

template <int C>
__global__ void k_scatter(const int* __restrict__ e, const int* __restrict__ flag,
                          const float* __restrict__ dinv, const float* __restrict__ h,
                          float* __restrict__ out, int E) {
  constexpr int TPE = C / 4;
  long long gid = (long long)blockIdx.x * blockDim.x + threadIdx.x;
  int ei = (int)(gid / TPE);
  int cq = (int)(gid % TPE);
  if (ei >= E) return;
  int m = *flag;
  int s, d;
  if (m) { s = e[2 * ei]; d = e[2 * (E + ei)]; }
  else   { s = e[ei];     d = e[E + ei]; }
  float nrm = dinv[s] * dinv[d];
  float4 v = ((const float4*)h)[(long long)s * TPE + cq];
  float* op = out + (long long)d * C + (long long)cq * 4;
  unsafeAtomicAdd(op + 0, v.x * nrm);
  unsafeAtomicAdd(op + 1, v.y * nrm);
  unsafeAtomicAdd(op + 2, v.z * nrm);
  unsafeAtomicAdd(op + 3, v.w * nrm);
}

extern "C" void kernel_launch(void* const* d_in, const int* in_sizes, int n_in,
                              void* d_out, int out_size, void* d_ws, size_t ws_size,
                              hipStream_t stream) {
  const float* x  = (const float*)d_in[0];
  const int*   e  = (const int*)d_in[1];
  const float* W1 = (const float*)d_in[2];
  const float* b1 = (const float*)d_in[3];
  const float* W2 = (const float*)d_in[4];
  const float* b2 = (const float*)d_in[5];
  float* out = (float*)d_out;
  const int E = in_sizes[1] / 2;

  char* ws = (char*)d_ws;
  const size_t o_flag    = 0;         // 16
  const size_t o_dinv    = 16;        // 400,000
  const size_t o_rowptr  = 400016;    // 400,004 (NN+1)
  const size_t o_gcur    = 800032;    // 784
  const size_t o_tmp     = 800832;    // 196*16384*4 = 12,845,056
  const size_t o_srcs    = 13645888;  // 6,400,000
  const size_t o_wt1     = 20045888;  // 32,768
  const size_t o_wt2     = 20078656;  // 16,384
  const size_t o_h       = 20095040;  // fp16 h table (row-major): 25,600,000
  const size_t o_h2      = 45695040;  // fp16 h2 table (row-major): 12,800,000
  const size_t need_csr  = 58495040;

  int*      flag   = (int*)(ws + o_flag);
  float*    dinv   = (float*)(ws + o_dinv);
  int*      rowptr = (int*)(ws + o_rowptr);
  int*      gcur   = (int*)(ws + o_gcur);
  unsigned* tmp    = (unsigned*)(ws + o_tmp);
  int*      srcs   = (int*)(ws + o_srcs);
  _Float16* wt1    = (_Float16*)(ws + o_wt1);
  _Float16* wt2    = (_Float16*)(ws + o_wt2);
  _Float16* hh     = (_Float16*)(ws + o_h);
  _Float16* h2     = (_Float16*)(ws + o_h2);

  if (ws_size >= need_csr) {
    // ---- CSR gather path: R8 structure + lean fused gather1/GEMM2 ----
    const int nA = (E + 4095) / 4096;  // 391
    const int nG = (NN + 63) / 64;     // 1563
    (void)hipMemsetAsync(gcur, 0, NBKT * sizeof(int), stream);
    k_binA<<<nA + 96, 256, 0, stream>>>(e, W1, W2, wt1, wt2, gcur, tmp, E, nA);
    k_binB<<<NBKT, 256, 0, stream>>>(tmp, gcur, rowptr, dinv, srcs);
    k_gemm1<<<nG, 256, 0, stream>>>(x, wt1, dinv, hh, NN);
    k_g1g2<<<nG, 256, 0, stream>>>(rowptr, srcs, dinv, hh, b1, wt2, h2, NN);
    k_gather2<<<(NN + 31) / 32, 256, 0, stream>>>(rowptr, srcs, dinv, h2, b2, out);
  } else {
    // ---- fallback: fp32 atomic scatter path ----
    int*   deg   = (int*)(ws + 400016);
    float* hF    = (float*)(ws + (1 << 20));
    float* out1F = (float*)(ws + (1 << 20) + 51200000);
    k_detect_f<<<1, 64, 0, stream>>>(e, flag, E);
    k_zero_i32<<<(NN + 255) / 256, 256, 0, stream>>>(deg, NN);
    k_deg_count<<<(E + 255) / 256, 256, 0, stream>>>(e, flag, deg, E);
    k_dinv_f<<<(NN + 255) / 256, 256, 0, stream>>>(deg, dinv);
    k_gemm_v<128, false><<<(NN + 31) / 32, 256, 0, stream>>>(x, W1, hF, NN);
    k_self_bias<128><<<(NN * 32 + 255) / 256, 256, 0, stream>>>(hF, dinv, b1, out1F);
    long long tot1 = (long long)E * 32;
    k_scatter<128><<<(int)((tot1 + 255) / 256), 256, 0, stream>>>(e, flag, dinv, hF, out1F, E);
    k_gemm_v<64, true><<<(NN + 63) / 64, 256, 0, stream>>>(out1F, W2, hF, NN);
    k_self_bias<64><<<(NN * 16 + 255) / 256, 256, 0, stream>>>(hF, dinv, b2, out);
    long long tot2 = (long long)E * 16;
    k_scatter<64><<<(int)((tot2 + 255) / 256), 256, 0, stream>>>(e, flag, dinv, hF, out, E);
  }
}

// Round 15
// 221.903 us; speedup vs baseline: 1.0796x; 1.0796x over previous
//
#include <hip/hip_runtime.h>
#include <hip/hip_fp16.h>

#define NN 100000
#define NBKT 196   // ceil(NN/512)
#define BCAP 16384 // slack per bucket (mean 8163, sigma ~90 for E=1.6M)

using f16x8 = __attribute__((ext_vector_type(8))) _Float16;
using f32x4 = __attribute__((ext_vector_type(4))) float;

// ---------------- helpers ----------------
__device__ __forceinline__ void fma4(float4& a, float s, const float4& w) {
  a.x = fmaf(s, w.x, a.x);
  a.y = fmaf(s, w.y, a.y);
  a.z = fmaf(s, w.z, a.z);
  a.w = fmaf(s, w.w, a.w);
}

// a[0..8) += cvt(8 halves)
__device__ __forceinline__ void add8(float* a, uint4 q) {
  const __half2* p = (const __half2*)&q;
#pragma unroll
  for (int j = 0; j < 4; ++j) {
    float2 f = __half22float2(p[j]);
    a[2 * j]     += f.x;
    a[2 * j + 1] += f.y;
  }
}

__device__ __forceinline__ unsigned packh2(float x, float y) {
  __half2 h = __floats2half2_rn(x, y);
  return *(unsigned*)&h;
}

// Stage A + prep fused.
// blocks [0,nA): bin 4096 edges each into NBKT dst-buckets (slack regions).
// blocks [nA,nA+64): W1 -> wt1 fp16 [n][k].  [nA+64,nA+96): W2 -> wt2.
__global__ __launch_bounds__(256) void k_binA(const int* __restrict__ e,
                                              const float* __restrict__ W1,
                                              const float* __restrict__ W2,
                                              _Float16* __restrict__ wt1,
                                              _Float16* __restrict__ wt2,
                                              int* __restrict__ gcur,
                                              unsigned int* __restrict__ tmp,
                                              int E, int nA) {
  const int b = blockIdx.x;
  const int tid = threadIdx.x;
  if (b >= nA) {  // weight conversion
    int wb = b - nA;
    if (wb < 64) {
      int i = wb * 256 + tid;
      int n = i >> 7, k = i & 127;
      wt1[i] = (_Float16)W1[k * 128 + n];
    } else {
      int i = (wb - 64) * 256 + tid;
      int n = i >> 7, k = i & 127;
      wt2[i] = (_Float16)W2[k * 64 + n];
    }
    return;
  }
  __shared__ int cnt[256];
  __shared__ int pcur[256];
  __shared__ int sm_flag;
  cnt[tid] = 0;
  if (tid < 64) {  // wave 0: detect int64 layout (odd words all zero)
    int n64 = E < 64 ? E : 64;
    int odd = (tid < n64) ? e[2 * tid + 1] : 0;
    unsigned long long nz = __ballot(odd != 0);
    if (tid == 0) sm_flag = (nz == 0ull) ? 1 : 0;
  }
  __syncthreads();
  const int m = sm_flag;
  const bool pok = ((E & 1) == 0);
  const int start = b * 4096;
  int ss[16], dd[16];
#pragma unroll
  for (int k = 0; k < 8; ++k) {
    int i = start + 2 * (tid + k * 256);
    int s0 = -1, s1 = -1, d0 = 0, d1 = 0;
    if (i < E) {
      if (m) {
        if (pok) {
          int4 sp = ((const int4*)e)[i >> 1];
          int4 dp = ((const int4*)e)[(E + i) >> 1];
          s0 = sp.x; s1 = sp.z; d0 = dp.x; d1 = dp.z;
        } else {
          s0 = (int)((const long long*)e)[i];
          d0 = (int)((const long long*)e)[E + i];
          if (i + 1 < E) {
            s1 = (int)((const long long*)e)[i + 1];
            d1 = (int)((const long long*)e)[E + i + 1];
          }
        }
      } else {
        if (pok) {
          int2 sp = ((const int2*)e)[i >> 1];
          int2 dp = ((const int2*)(e + E))[i >> 1];
          s0 = sp.x; s1 = sp.y; d0 = dp.x; d1 = dp.y;
        } else {
          s0 = e[i]; d0 = e[E + i];
          if (i + 1 < E) { s1 = e[i + 1]; d1 = e[E + i + 1]; }
        }
      }
      if (i + 1 >= E) s1 = -1;
      atomicAdd(&cnt[d0 >> 9], 1);
      if (s1 >= 0) atomicAdd(&cnt[d1 >> 9], 1);
    }
    ss[2 * k] = s0; dd[2 * k] = d0;
    ss[2 * k + 1] = s1; dd[2 * k + 1] = d1;
  }
  __syncthreads();
  if (tid < NBKT && cnt[tid] > 0)
    pcur[tid] = tid * BCAP + atomicAdd(&gcur[tid], cnt[tid]);
  __syncthreads();
#pragma unroll
  for (int k = 0; k < 16; ++k) {
    if (ss[k] >= 0) {
      int bk = dd[k] >> 9;
      int p = atomicAdd(&pcur[bk], 1);
      tmp[p] = ((unsigned)ss[k] << 9) | (unsigned)(dd[k] & 511);
    }
  }
}

// Stage B (scan fused): per bucket, redundant 196-count scan -> base/total;
// LDS histogram (= deg) -> dinv + rowptr; local scan; place srcs.
__global__ __launch_bounds__(256) void k_binB(const unsigned int* __restrict__ tmp,
                                              const int* __restrict__ gcur,
                                              int* __restrict__ rowptr,
                                              float* __restrict__ dinv,
                                              int* __restrict__ srcs) {
  __shared__ int sbuf[256];
  __shared__ int hist[512];
  __shared__ int lofs[512];
  const int b = blockIdx.x;
  const int tid = threadIdx.x;
  int c = (tid < NBKT) ? gcur[tid] : 0;
  sbuf[tid] = c;
  __syncthreads();
#pragma unroll
  for (int off = 1; off < 256; off <<= 1) {
    int t = (tid >= off) ? sbuf[tid - off] : 0;
    __syncthreads();
    sbuf[tid] += t;
    __syncthreads();
  }
  const int total = sbuf[255];
  const int incl = sbuf[b];
  const int base_b = (b > 0) ? sbuf[b - 1] : 0;
  const int cntb = incl - base_b;
  if (b == 0 && tid == 0) rowptr[NN] = total;
  __syncthreads();
  hist[tid] = 0;
  hist[tid + 256] = 0;
  __syncthreads();
  const int tbeg = b * BCAP;
  const int tend = tbeg + cntb;
  for (int j = tbeg + tid; j < tend; j += 256) atomicAdd(&hist[tmp[j] & 511], 1);
  __syncthreads();
  int a0 = hist[2 * tid], a1 = hist[2 * tid + 1];
  int sv = a0 + a1;
  sbuf[tid] = sv;
  __syncthreads();
#pragma unroll
  for (int off = 1; off < 256; off <<= 1) {
    int t = (tid >= off) ? sbuf[tid - off] : 0;
    __syncthreads();
    sbuf[tid] += t;
    __syncthreads();
  }
  int excl = sbuf[tid] - sv;
  lofs[2 * tid] = excl;
  lofs[2 * tid + 1] = excl + a0;
  __syncthreads();
  for (int i = tid; i < 512; i += 256) {
    int node = (b << 9) + i;
    if (node < NN) {
      rowptr[node] = base_b + lofs[i];
      dinv[node] = rsqrtf((float)(hist[i] + 1));
    }
  }
  __syncthreads();
  for (int j = tbeg + tid; j < tend; j += 256) {
    unsigned v = tmp[j];
    int p = base_b + atomicAdd(&lofs[v & 511], 1);
    srcs[p] = (int)(v >> 9);
  }
}

// C[M,N] = A[M,128] @ W[128,N] via mfma_f32_16x16x32_f16.
// Epilogue scales row by dinv[row] (pre-scaled message table), fp16 out.
template <int N, bool AHALF>
__global__ __launch_bounds__(256) void k_gemm_mfma(const void* __restrict__ Av,
                                                   const _Float16* __restrict__ Wt,
                                                   const float* __restrict__ dinv,
                                                   _Float16* __restrict__ out, int M) {
  constexpr int NF = N / 16;
  __shared__ _Float16 As[64 * 136];
  __shared__ _Float16 Bs[N * 136];
  const int tid = threadIdx.x;
  const long long row0 = (long long)blockIdx.x * 64;
  if (AHALF) {
    const _Float16* A = (const _Float16*)Av;
#pragma unroll
    for (int t = 0; t < 4; ++t) {
      int i = tid + t * 256;  // 1024 uint4 (8 halves each)
      int m = i >> 4, q = i & 15;
      long long row = row0 + m;
      uint4 v = make_uint4(0, 0, 0, 0);
      if (row < M) v = ((const uint4*)A)[row * 16 + q];
      *(uint4*)&As[m * 136 + q * 8] = v;
    }
  } else {
    const float* A = (const float*)Av;
#pragma unroll
    for (int t = 0; t < 8; ++t) {
      int i = tid + t * 256;  // 2048 float4
      int m = i >> 5, q = i & 31;
      long long row = row0 + m;
      float4 v = make_float4(0.f, 0.f, 0.f, 0.f);
      if (row < M) v = ((const float4*)A)[row * 32 + q];
      uint2 w2 = make_uint2(packh2(v.x, v.y), packh2(v.z, v.w));
      *(uint2*)&As[m * 136 + q * 4] = w2;
    }
  }
#pragma unroll
  for (int t = 0; t < N / 16; ++t) {
    int i = tid + t * 256;
    int n = i >> 4, q = i & 15;
    uint4 v = ((const uint4*)Wt)[i];
    *(uint4*)&Bs[n * 136 + q * 8] = v;
  }
  __syncthreads();
  const int lane = tid & 63;
  const int wrow = (tid >> 6) * 16;
  const int r = lane & 15, g = lane >> 4;
  f32x4 acc[NF] = {};
#pragma unroll
  for (int ks = 0; ks < 4; ++ks) {
    f16x8 av = *(const f16x8*)&As[(wrow + r) * 136 + ks * 32 + g * 8];
#pragma unroll
    for (int cf = 0; cf < NF; ++cf) {
      f16x8 bv = *(const f16x8*)&Bs[(cf * 16 + r) * 136 + ks * 32 + g * 8];
      acc[cf] = __builtin_amdgcn_mfma_f32_16x16x32_f16(av, bv, acc[cf], 0, 0, 0);
    }
  }
#pragma unroll
  for (int q = 0; q < 4; ++q) {
    long long row = row0 + wrow + g * 4 + q;
    if (row < M) {
      float sc = dinv[row];
#pragma unroll
      for (int cf = 0; cf < NF; ++cf)
        out[row * N + cf * 16 + r] = (_Float16)(sc * acc[cf][q]);
    }
  }
}

// Gather-reduce over pre-scaled table: out[d] = dd*(sum rows incl. self) + b.
// RELU16: relu + fp16 out (layer 1); else fp32 out (final).
template <int C, bool RELU16>
__global__ __launch_bounds__(256) void k_gather_s(const int* __restrict__ rowptr,
                                                  const int* __restrict__ srcs,
                                                  const float* __restrict__ dinv,
                                                  const _Float16* __restrict__ h,
                                                  const float* __restrict__ b,
                                                  void* __restrict__ outv) {
  constexpr int LPN = C / 8;
  constexpr int NPW = 64 / LPN;
  constexpr int NPB = NPW * 4;
  const int wave = threadIdx.x >> 6;
  const int lane = threadIdx.x & 63;
  const int grp = lane / LPN;
  const int li = lane % LPN;
  const int node = blockIdx.x * NPB + wave * NPW + grp;
  if (node >= NN) return;
  const float dd = dinv[node];
  float acc[8];
  {
    uint4 q = *(const uint4*)(h + (long long)node * C + li * 8);
    const __half2* p = (const __half2*)&q;
#pragma unroll
    for (int j = 0; j < 4; ++j) {
      float2 f = __half22float2(p[j]);
      acc[2 * j]     = f.x;
      acc[2 * j + 1] = f.y;
    }
  }
  const int beg = rowptr[node], end = rowptr[node + 1];
  int e = beg;
  for (; e + 4 <= end; e += 4) {
    int s0 = srcs[e], s1 = srcs[e + 1], s2 = srcs[e + 2], s3 = srcs[e + 3];
    uint4 q0 = *(const uint4*)(h + (long long)s0 * C + li * 8);
    uint4 q1 = *(const uint4*)(h + (long long)s1 * C + li * 8);
    uint4 q2 = *(const uint4*)(h + (long long)s2 * C + li * 8);
    uint4 q3 = *(const uint4*)(h + (long long)s3 * C + li * 8);
    add8(acc, q0);
    add8(acc, q1);
    add8(acc, q2);
    add8(acc, q3);
  }
  for (; e < end; ++e) {
    uint4 q0 = *(const uint4*)(h + (long long)srcs[e] * C + li * 8);
    add8(acc, q0);
  }
  const float4* b4 = (const float4*)b;
  float4 bb0 = b4[li * 2], bb1 = b4[li * 2 + 1];
  float o[8];
  o[0] = fmaf(dd, acc[0], bb0.x);
  o[1] = fmaf(dd, acc[1], bb0.y);
  o[2] = fmaf(dd, acc[2], bb0.z);
  o[3] = fmaf(dd, acc[3], bb0.w);
  o[4] = fmaf(dd, acc[4], bb1.x);
  o[5] = fmaf(dd, acc[5], bb1.y);
  o[6] = fmaf(dd, acc[6], bb1.z);
  o[7] = fmaf(dd, acc[7], bb1.w);
  if (RELU16) {
#pragma unroll
    for (int j = 0; j < 8; ++j) o[j] = fmaxf(o[j], 0.f);
    uint4 w;
    w.x = packh2(o[0], o[1]);
    w.y = packh2(o[2], o[3]);
    w.z = packh2(o[4], o[5]);
    w.w = packh2(o[6], o[7]);
    *(uint4*)((_Float16*)outv + (long long)node * C + li * 8) = w;
  } else {
    float4* op = (float4*)((float*)outv + (long long)node * C + li * 8);
    op[0] = make_float4(o[0], o[1], o[2], o[3]);
    op[1] = make_float4(o[4], o[5], o[6], o[7]);
  }
}

// ---------------- fallback (atomic scatter, fp32) kernels ----------------
__global__ void k_zero_i32(int* p, int n) {
  int i = blockIdx.x * 256 + threadIdx.x;
  if (i < n) p[i] = 0;
}

__global__ void k_detect_f(const int* __restrict__ e, int* flag, int E) {
  if (threadIdx.x == 0 && blockIdx.x == 0) {
    int n = E < 64 ? E : 64;
    int m = 1;
    for (int i = 0; i < n; ++i)
      if (e[2 * i + 1] != 0) { m = 0; break; }
    *flag = m;
  }
}

__global__ void k_deg_count(const int* __restrict__ e, const int* __restrict__ flag,
                            int* __restrict__ deg, int E) {
  int i = blockIdx.x * 256 + threadIdx.x;
  if (i >= E) return;
  int m = *flag;
  int d = m ? e[2 * (E + i)] : e[E + i];
  atomicAdd(&deg[d], 1);
}

__global__ void k_dinv_f(const int* __restrict__ deg, float* __restrict__ dinv) {
  int i = blockIdx.x * 256 + threadIdx.x;
  if (i < NN) dinv[i] = rsqrtf((float)(deg[i] + 1));
}

template <int N, bool RELU>
__global__ __launch_bounds__(256) void k_gemm_v(const float* __restrict__ A,
                                                const float* __restrict__ W,
                                                float* __restrict__ out, int M) {
  constexpr int K4 = 32;
  constexpr int N4 = N / 4;
  constexpr int CG = N4;
  constexpr int ROWS = (256 / CG) * 4;
  __shared__ float4 Wl[128 * N4];
  __shared__ float4 Xl[ROWS * K4];
  const int tid = threadIdx.x;
  const float4* W4 = (const float4*)W;
  for (int i = tid; i < 128 * N4; i += 256) Wl[i] = W4[i];
  const long long row0 = (long long)blockIdx.x * ROWS;
  const float4* A4 = (const float4*)A;
  for (int i = tid; i < ROWS * K4; i += 256) {
    int r = i >> 5;
    long long row = row0 + r;
    float4 v = make_float4(0.f, 0.f, 0.f, 0.f);
    if (row < M) v = A4[row * K4 + (i & 31)];
    if (RELU) {
      v.x = fmaxf(v.x, 0.f); v.y = fmaxf(v.y, 0.f);
      v.z = fmaxf(v.z, 0.f); v.w = fmaxf(v.w, 0.f);
    }
    Xl[i] = v;
  }
  __syncthreads();
  const int c = tid % CG;
  const int rb = (tid / CG) * 4;
  float4 a0 = make_float4(0, 0, 0, 0), a1 = a0, a2 = a0, a3 = a0;
#pragma unroll 4
  for (int k4 = 0; k4 < K4; ++k4) {
    float4 w0 = Wl[(k4 * 4 + 0) * N4 + c];
    float4 w1 = Wl[(k4 * 4 + 1) * N4 + c];
    float4 w2 = Wl[(k4 * 4 + 2) * N4 + c];
    float4 w3 = Wl[(k4 * 4 + 3) * N4 + c];
    float4 x0 = Xl[(rb + 0) * K4 + k4];
    float4 x1 = Xl[(rb + 1) * K4 + k4];
    float4 x2 = Xl[(rb + 2) * K4 + k4];
    float4 x3 = Xl[(rb + 3) * K4 + k4];
    fma4(a0, x0.x, w0); fma4(a0, x0.y, w1); fma4(a0, x0.z, w2); fma4(a0, x0.w, w3);
    fma4(a1, x1.x, w0); fma4(a1, x1.y, w1); fma4(a1, x1.z, w2); fma4(a1, x1.w, w3);
    fma4(a2, x2.x, w0); fma4(a2, x2.y, w1); fma4(a2, x2.z, w2); fma4(a2, x2.w, w3);
    fma4(a3, x3.x, w0); fma4(a3, x3.y, w1); fma4(a3, x3.z, w2); fma4(a3, x3.w, w3);
  }
  float4* O4 = (float4*)out;
  long long row = row0 + rb;
  if (row + 0 < M) O4[(row + 0) * N4 + c] = a0;
  if (row + 1 < M) O4[(row + 1) * N4 + c] = a1;
  if (row + 2 < M) O4[(row + 2) * N4 + c] = a2;
  if (row + 3 < M) O4[(row + 3) * N4 + c] = a3;
}

template <int C>
__global__ void k_self_bias(const float* __restrict__ h, const float* __restrict__ dinv,
                            const float* __restrict__ b, float* __restrict__ out) {
  constexpr int C4 = C / 4;
  int gid = blockIdx.x * 256 + threadIdx.x;
  if (gid >= NN * C4) return;
  int node = gid / C4;
  int cq = gid % C4;
  float di = dinv[node];
  float sc = di * di;
  float4 v = ((const float4*)h)[gid];
  float4 bb = ((const float4*)b)[cq];
  float4 o;
  o.x = fmaf(v.x, sc, bb.x);
  o.y = fmaf(v.y, sc, bb.y);
  o.z = fmaf(v.z, sc, bb.z);
  o.w = fmaf(v.w, sc, bb.w);
  ((float4*)out)[gid] = o;
}

template <int C>
__global__ void k_scatter(const int* __restrict__ e, const int* __restrict__ flag,
                          const float* __restrict__ dinv, const float* __restrict__ h,
                          float* __restrict__ out, int E) {
  constexpr int TPE = C / 4;
  long long gid = (long long)blockIdx.x * blockDim.x + threadIdx.x;
  int ei = (int)(gid / TPE);
  int cq = (int)(gid % TPE);
  if (ei >= E) return;
  int m = *flag;
  int s, d;
  if (m) { s = e[2 * ei]; d = e[2 * (E + ei)]; }
  else   { s = e[ei];     d = e[E + ei]; }
  float nrm = dinv[s] * dinv[d];
  float4 v = ((const float4*)h)[(long long)s * TPE + cq];
  float* op = out + (long long)d * C + (long long)cq * 4;
  unsafeAtomicAdd(op + 0, v.x * nrm);
  unsafeAtomicAdd(op + 1, v.y * nrm);
  unsafeAtomicAdd(op + 2, v.z * nrm);
  unsafeAtomicAdd(op + 3, v.w * nrm);
}

extern "C" void kernel_launch(void* const* d_in, const int* in_sizes, int n_in,
                              void* d_out, int out_size, void* d_ws, size_t ws_size,
                              hipStream_t stream) {
  const float* x  = (const float*)d_in[0];
  const int*   e  = (const int*)d_in[1];
  const float* W1 = (const float*)d_in[2];
  const float* b1 = (const float*)d_in[3];
  const float* W2 = (const float*)d_in[4];
  const float* b2 = (const float*)d_in[5];
  float* out = (float*)d_out;
  const int E = in_sizes[1] / 2;

  char* ws = (char*)d_ws;
  const size_t o_flag    = 0;         // 16
  const size_t o_dinv    = 16;        // 400,000
  const size_t o_rowptr  = 400016;    // 400,004 (NN+1)
  const size_t o_gcur    = 800032;    // 784
  const size_t o_tmp     = 800832;    // 196*16384*4 = 12,845,056
  const size_t o_srcs    = 13645888;  // 6,400,000
  const size_t o_wt1     = 20045888;  // 32,768
  const size_t o_wt2     = 20078656;  // 16,384
  const size_t o_h       = 20095040;  // fp16 h (row-major): 25,600,000
  const size_t o_out1    = 45695040;  // fp16 out1 (row-major): 25,600,000
  const size_t need_csr  = 71295040;

  int*      flag   = (int*)(ws + o_flag);
  float*    dinv   = (float*)(ws + o_dinv);
  int*      rowptr = (int*)(ws + o_rowptr);
  int*      gcur   = (int*)(ws + o_gcur);
  unsigned* tmp    = (unsigned*)(ws + o_tmp);
  int*      srcs   = (int*)(ws + o_srcs);
  _Float16* wt1    = (_Float16*)(ws + o_wt1);
  _Float16* wt2    = (_Float16*)(ws + o_wt2);
  _Float16* hh     = (_Float16*)(ws + o_h);
  _Float16* out1   = (_Float16*)(ws + o_out1);

  if (ws_size >= need_csr) {
    // ---- CSR gather path: fused binned build, pre-scaled fp16, MFMA ----
    const int nA = (E + 4095) / 4096;
    (void)hipMemsetAsync(gcur, 0, NBKT * sizeof(int), stream);
    k_binA<<<nA + 96, 256, 0, stream>>>(e, W1, W2, wt1, wt2, gcur, tmp, E, nA);
    k_binB<<<NBKT, 256, 0, stream>>>(tmp, gcur, rowptr, dinv, srcs);

    k_gemm_mfma<128, false><<<(NN + 63) / 64, 256, 0, stream>>>(x, wt1, dinv, hh, NN);
    k_gather_s<128, true><<<(NN + 15) / 16, 256, 0, stream>>>(rowptr, srcs, dinv, hh, b1, out1);

    k_gemm_mfma<64, true><<<(NN + 63) / 64, 256, 0, stream>>>(out1, wt2, dinv, hh, NN);
    k_gather_s<64, false><<<(NN + 31) / 32, 256, 0, stream>>>(rowptr, srcs, dinv, hh, b2, out);
  } else {
    // ---- fallback: fp32 atomic scatter path ----
    int*   deg   = (int*)(ws + 400016);
    float* hF    = (float*)(ws + (1 << 20));
    float* out1F = (float*)(ws + (1 << 20) + 51200000);
    k_detect_f<<<1, 64, 0, stream>>>(e, flag, E);
    k_zero_i32<<<(NN + 255) / 256, 256, 0, stream>>>(deg, NN);
    k_deg_count<<<(E + 255) / 256, 256, 0, stream>>>(e, flag, deg, E);
    k_dinv_f<<<(NN + 255) / 256, 256, 0, stream>>>(deg, dinv);
    k_gemm_v<128, false><<<(NN + 31) / 32, 256, 0, stream>>>(x, W1, hF, NN);
    k_self_bias<128><<<(NN * 32 + 255) / 256, 256, 0, stream>>>(hF, dinv, b1, out1F);
    long long tot1 = (long long)E * 32;
    k_scatter<128><<<(int)((tot1 + 255) / 256), 256, 0, stream>>>(e, flag, dinv, hF, out1F, E);
    k_gemm_v<64, true><<<(NN + 63) / 64, 256, 0, stream>>>(out1F, W2, hF, NN);
    k_self_bias<64><<<(NN * 16 + 255) / 256, 256, 0, stream>>>(hF, dinv, b2, out);
    long long tot2 = (long long)E * 16;
    k_scatter<64><<<(int)((tot2 + 255) / 256), 256, 0, stream>>>(e, flag, dinv, hF, out, E);
  }
}